// Round 6
// baseline (355.713 us; speedup 1.0000x reference)
//
#include <hip/hip_runtime.h>
#include <hip/hip_fp16.h>
#include <math.h>

#define NN 20000
#define NE 320000
#define NB 128
#define SLOPE 0.2f
#define BN_EPS 1e-5f
#define NBLK 79   // ceil(NN/256)
#define PBKT 256  // BN partial bucket rows
#define ROWS_H 33 // half-tile LDS row stride (floats): (el+k)%32 -> 2-way, free

__device__ __forceinline__ unsigned short f2bf(float f) {
    unsigned int u = __float_as_uint(f);
    unsigned int r = (u + 0x7FFFu + ((u >> 16) & 1u)) >> 16;
    return (unsigned short)r;
}
__device__ __forceinline__ float bf2f(unsigned short h) {
    return __uint_as_float(((unsigned int)h) << 16);
}

// ---------- fused front: hist (0..1249) + insl (1250..1377) + ve/ce (1378..1379) ----------
// ve now written TRANSPOSED into veT[64] float4: veT[k] = {L0h0, L0h1, L1h0, L1h1}[k]
__global__ __launch_bounds__(256) void k_front(const int* __restrict__ dst, int* __restrict__ deg,
                                               const float* __restrict__ instr, const float* __restrict__ Wl,
                                               const float* __restrict__ We, const float* __restrict__ atte,
                                               float* __restrict__ insl01, float* __restrict__ veTf,
                                               float* __restrict__ ce01) {
    __shared__ float w2[128];
    int blk = blockIdx.x, t = threadIdx.x;
    if (blk < 1250) {
        int e = blk * 256 + t;
        atomicAdd(&deg[dst[e]], 1);
    } else if (blk < 1378) {
        int bb = blk - 1250;
        int L = bb >> 6;
        int idx = (bb & 63) * 256 + t;
        int b = idx >> 7, j = idx & 127;
        const float* ins = instr + (size_t)L * NB * 64;
        const float* WlL = Wl + (size_t)L * 128 * 128;
        float acc = 0.f;
        for (int k = 0; k < 64; ++k) acc += ins[b * 64 + k] * WlL[(64 + k) * 128 + j];
        insl01[(size_t)L * 16384 + idx] = acc;
    } else {
        int L = blk - 1378;
        const float* WeL = We + (size_t)L * 128 * 128;
        const float* aeL = atte + L * 128;
        int h = (t >> 6) & 1;
        int k = t & 63;
        int row = (t < 128) ? k : (64 + k);
        float acc = 0.f;
        for (int c = 0; c < 64; ++c) acc += WeL[row * 128 + h * 64 + c] * aeL[h * 64 + c];
        if (t < 128) veTf[k * 4 + L * 2 + h] = acc;   // transposed packing for sced scalar loads
        else        w2[t - 128] = acc;
        __syncthreads();
        int b = t >> 1, hh = t & 1;
        const float* ins = instr + (size_t)L * NB * 64;
        float a2 = 0.f;
        for (int kk = 0; kk < 64; ++kk) a2 += ins[b * 64 + kk] * w2[hh * 64 + kk];
        ce01[L * 256 + b * 2 + hh] = a2;
    }
}

// ---------- CSR scan (proven 3-kernel chain, round-0 verbatim) ----------
__global__ __launch_bounds__(256) void k_scanA(const int* __restrict__ deg, int* __restrict__ bsum) {
    __shared__ int wsum[4];
    int t = threadIdx.x;
    int idx = blockIdx.x * 256 + t;
    int v = (idx < NN) ? deg[idx] : 0;
    for (int off = 32; off > 0; off >>= 1) v += __shfl_xor(v, off);
    if ((t & 63) == 0) wsum[t >> 6] = v;
    __syncthreads();
    if (t == 0) bsum[blockIdx.x] = wsum[0] + wsum[1] + wsum[2] + wsum[3];
}

__global__ __launch_bounds__(64) void k_scanB(const int* __restrict__ bsum, int* __restrict__ boff,
                                              int* __restrict__ rowptr) {
    int l = threadIdx.x;
    int v0 = (l < NBLK) ? bsum[l] : 0;
    int v1 = (64 + l < NBLK) ? bsum[64 + l] : 0;
    int o0 = v0, o1 = v1;
    for (int off = 1; off < 64; off <<= 1) { int u = __shfl_up(v0, off); if (l >= off) v0 += u; }
    int tot0 = __shfl(v0, 63);
    for (int off = 1; off < 64; off <<= 1) { int u = __shfl_up(v1, off); if (l >= off) v1 += u; }
    int tot1 = __shfl(v1, 63);
    if (l < NBLK) boff[l] = v0 - o0;
    if (64 + l < NBLK) boff[64 + l] = tot0 + v1 - o1;
    if (l == 0) rowptr[NN] = tot0 + tot1;
}

__global__ __launch_bounds__(256) void k_scanC(const int* __restrict__ deg, const int* __restrict__ boff,
                                               int* __restrict__ rowptr, int* __restrict__ cursor) {
    __shared__ int wsum[4];
    int t = threadIdx.x, lane = t & 63, w = t >> 6;
    int idx = blockIdx.x * 256 + t;
    int v = (idx < NN) ? deg[idx] : 0;
    int incl = v;
    for (int off = 1; off < 64; off <<= 1) { int u = __shfl_up(incl, off); if (lane >= off) incl += u; }
    if (lane == 63) wsum[w] = incl;
    __syncthreads();
    int pre = 0;
    for (int i = 0; i < w; ++i) pre += wsum[i];
    int excl = incl - v + pre + boff[blockIdx.x];
    if (idx < NN) { rowptr[idx] = excl; cursor[idx] = excl; }
}

// ---------- node linear: xl (bf16) + alc + ar; float4 LDS broadcast reads ----------
__global__ __launch_bounds__(256) void k_node(const float* __restrict__ hcur, const float* __restrict__ Wl,
                                              const float* __restrict__ insl, const int* __restrict__ batch,
                                              const float* __restrict__ attl, const float* __restrict__ attr_,
                                              const float2* __restrict__ ce2,
                                              const float* __restrict__ scsh, int use_bn,
                                              unsigned short* __restrict__ xlh,
                                              float* __restrict__ alc, float* __restrict__ ar) {
    __shared__ float sh[8 * 64];
    int t = threadIdx.x;
    int row0 = blockIdx.x * 8;
    for (int idx = t; idx < 512; idx += 256) {
        int r = idx >> 6, k = idx & 63;
        int n = row0 + r;
        float hv = (n < NN) ? hcur[n * 64 + k] : 0.f;
        if (use_bn) hv = fmaxf(hv * scsh[k] + scsh[64 + k], 0.f);
        sh[idx] = hv;
    }
    __syncthreads();
    int w = t >> 6, lane = t & 63;
    int h = w & 1;
    int rbase = (w >> 1) * 4;
    int j = h * 64 + lane;
    float attlv = attl[j];
    float attrv = attr_[j];
    const float4* sh4 = (const float4*)sh;
    int rb16 = rbase * 16;
    float acc0 = 0.f, acc1 = 0.f, acc2 = 0.f, acc3 = 0.f;
#pragma unroll
    for (int k4 = 0; k4 < 16; ++k4) {
        int kb = k4 << 2;
        float w0 = Wl[(kb + 0) * 128 + j];
        float w1 = Wl[(kb + 1) * 128 + j];
        float w2v = Wl[(kb + 2) * 128 + j];
        float w3 = Wl[(kb + 3) * 128 + j];
        float4 r0 = sh4[rb16 + k4];
        float4 r1 = sh4[rb16 + 16 + k4];
        float4 r2 = sh4[rb16 + 32 + k4];
        float4 r3 = sh4[rb16 + 48 + k4];
        acc0 += r0.x * w0; acc0 += r0.y * w1; acc0 += r0.z * w2v; acc0 += r0.w * w3;
        acc1 += r1.x * w0; acc1 += r1.y * w1; acc1 += r1.z * w2v; acc1 += r1.w * w3;
        acc2 += r2.x * w0; acc2 += r2.y * w1; acc2 += r2.z * w2v; acc2 += r2.w * w3;
        acc3 += r3.x * w0; acc3 += r3.y * w1; acc3 += r3.z * w2v; acc3 += r3.w * w3;
    }
    float accs[4] = {acc0, acc1, acc2, acc3};
    for (int rr = 0; rr < 4; ++rr) {
        int n = row0 + rbase + rr;
        if (n >= NN) break;
        int b = batch[n];
        float v = accs[rr] + insl[b * 128 + j];
        xlh[(size_t)n * 128 + j] = f2bf(v);
        float pl = v * attlv, pr = v * attrv;
        for (int off = 32; off > 0; off >>= 1) {
            pl += __shfl_xor(pl, off);
            pr += __shfl_xor(pr, off);
        }
        if (lane == 0) {
            float2 cb = ce2[b];
            alc[n * 2 + h] = pl + (h ? cb.y : cb.x);
            ar[n * 2 + h] = pr;
        }
    }
}

// ---------- edge kernel v6: half-tile LDS staging + veT via wave-uniform (scalar) loads ----------
__global__ __launch_bounds__(64) void k_sced(const int* __restrict__ src, const int* __restrict__ dst,
                                             const float* __restrict__ eattr, const float4* __restrict__ veT,
                                             const float2* __restrict__ alc2, const float2* __restrict__ ar2,
                                             int* __restrict__ cursor, int4* __restrict__ einfo) {
    __shared__ float se[64 * ROWS_H];   // 8448 B
    int lane = threadIdx.x;
    int ebase = blockIdx.x * 64;
    float d0 = 0.f, d1 = 0.f, d2 = 0.f, d3 = 0.f;
    const float* row = se + lane * ROWS_H;
#pragma unroll
    for (int half = 0; half < 2; ++half) {
        const float4* gsrc = (const float4*)eattr + (size_t)ebase * 16 + half * 8;
#pragma unroll
        for (int i = 0; i < 8; ++i) {
            int fi = i * 64 + lane;
            int el = fi >> 3, q = fi & 7;
            float4 f = gsrc[(size_t)el * 16 + q];
            float* dp = se + el * ROWS_H + q * 4;
            dp[0] = f.x; dp[1] = f.y; dp[2] = f.z; dp[3] = f.w;
        }
        // veT index is wave-uniform -> scalar-cache loads, LDS pipe freed
#pragma unroll
        for (int k = 0; k < 32; ++k) {
            float fv = row[k];
            float4 vt = veT[half * 32 + k];
            d0 += fv * vt.x; d1 += fv * vt.y; d2 += fv * vt.z; d3 += fv * vt.w;
        }
    }
    int e = ebase + lane;
    int s = src[e], dd = dst[e];
    float2 al = alc2[s], arr = ar2[dd];
    float a0 = al.x + arr.x + d0;
    float a1 = al.y + arr.y + d1;
    a0 = (a0 > 0.f) ? a0 : SLOPE * a0;
    a1 = (a1 > 0.f) ? a1 : SLOPE * a1;
    __half2 ex = __floats2half2_rn(__expf(a0), __expf(a1));
    __half2 d23 = __floats2half2_rn(d2, d3);
    int pos = atomicAdd(&cursor[dd], 1);
    einfo[pos] = make_int4(s | (dd << 15), *(int*)&d23, s, *(int*)&ex);
}

// ---------- layer-0 gather: weighted mean + bias + residual; BN partials via fence-free atomics ----------
__global__ __launch_bounds__(256) void k_gather0(const int* __restrict__ rowptr, const int2* __restrict__ rec,
                                                 const unsigned int* __restrict__ xl32,
                                                 const float* __restrict__ bias, const float* __restrict__ hprev,
                                                 float* __restrict__ hnew, float* __restrict__ part) {
    __shared__ float smv[4][64];
    __shared__ float smq[4][64];
    int t = threadIdx.x;
    int w = t >> 6, lane = t & 63;
    int n = blockIdx.x * 4 + w;
    int r0 = rowptr[n], r1 = rowptr[n + 1];
    float acc0 = 0.f, acc1 = 0.f, ss = 0.f;
    const unsigned int* xlp = xl32 + lane;
#pragma unroll 8
    for (int p = r0; p < r1; ++p) {
        int2 r = rec[(size_t)p * 2];
        __half2 hx = *(__half2*)&r.y;
        float2 e2 = __half22float2(hx);
        float ex = (lane < 32) ? e2.x : e2.y;
        unsigned int pr = xlp[(size_t)r.x * 64];
        ss += ex;
        acc0 += ex * bf2f((unsigned short)(pr & 0xFFFFu));
        acc1 += ex * bf2f((unsigned short)(pr >> 16));
    }
    float inv_s = 1.f / (ss + 1e-16f);
    acc0 *= inv_s; acc1 *= inv_s;
    float o0 = 0.5f * (acc0 + __shfl_xor(acc0, 32));
    float o1 = 0.5f * (acc1 + __shfl_xor(acc1, 32));
    if (lane < 32) {
        float2 hv = ((const float2*)(hprev + (size_t)n * 64))[lane];
        float2 bv = ((const float2*)bias)[lane];
        float2 o;
        o.x = o0 + bv.x + hv.x;
        o.y = o1 + bv.y + hv.y;
        ((float2*)(hnew + (size_t)n * 64))[lane] = o;
        smv[w][2 * lane]     = o.x;
        smv[w][2 * lane + 1] = o.y;
        smq[w][2 * lane]     = o.x * o.x;
        smq[w][2 * lane + 1] = o.y * o.y;
    }
    __syncthreads();
    if (t < 128) {
        int c = t & 63, which = t >> 6;
        float a = which ? (smq[0][c] + smq[1][c] + smq[2][c] + smq[3][c])
                        : (smv[0][c] + smv[1][c] + smv[2][c] + smv[3][c]);
        atomicAdd(&part[(blockIdx.x & (PBKT - 1)) * 128 + which * 64 + c], a);
    }
}

// ---------- BN finalize: reduce PBKT x 128 partials -> scsh ----------
__global__ __launch_bounds__(512) void k_bnfin(const float* __restrict__ part,
                                               const float* __restrict__ gamma, const float* __restrict__ beta,
                                               float* __restrict__ scsh) {
    __shared__ float red[512];
    __shared__ float tot[128];
    int t = threadIdx.x;
    int col = t & 127, q = t >> 7;
    float s = 0.f;
    for (int r = q * (PBKT / 4); r < (q + 1) * (PBKT / 4); ++r) s += part[r * 128 + col];
    red[t] = s;
    __syncthreads();
    if (t < 128) tot[t] = red[t] + red[t + 128] + red[t + 256] + red[t + 384];
    __syncthreads();
    if (t < 64) {
        float su = tot[t];
        float sq = tot[64 + t];
        float mu = su * (1.f / NN);
        float var = sq * (1.f / NN) - mu * mu;
        float sc = gamma[t] * rsqrtf(var + BN_EPS);
        scsh[t] = sc;
        scsh[64 + t] = beta[t] - mu * sc;
    }
}

// ---------- layer-1 logits + exp (CSR order, coalesced read/write) ----------
__global__ __launch_bounds__(256) void k_attnexp(const int4* __restrict__ einfo,
                                                 const float2* __restrict__ alc2, const float2* __restrict__ ar2,
                                                 int2* __restrict__ rec1) {
    int p = blockIdx.x * 256 + threadIdx.x;
    if (p >= NE) return;
    int4 r = einfo[p];
    int s = r.x & 0x7FFF, d = r.x >> 15;
    __half2 hd = *(__half2*)&r.y;
    float2 dv = __half22float2(hd);
    float2 a_l = alc2[s];
    float2 a_r = ar2[d];
    float a0 = a_l.x + a_r.x + dv.x;
    float a1 = a_l.y + a_r.y + dv.y;
    a0 = (a0 > 0.f) ? a0 : SLOPE * a0;
    a1 = (a1 > 0.f) ? a1 : SLOPE * a1;
    __half2 hx = __floats2half2_rn(__expf(a0), __expf(a1));
    rec1[p] = make_int2(s, *(int*)&hx);
}

// ---------- layer-1 gather: dense 8B rec; BN'd residual ----------
__global__ __launch_bounds__(256) void k_gather1(const int* __restrict__ rowptr, const int2* __restrict__ rec,
                                                 const unsigned int* __restrict__ xl32,
                                                 const float* __restrict__ bias, const float* __restrict__ hprev,
                                                 const float* __restrict__ scsh, float* __restrict__ out) {
    int t = threadIdx.x;
    int w = t >> 6, lane = t & 63;
    int n = blockIdx.x * 4 + w;
    int r0 = rowptr[n], r1 = rowptr[n + 1];
    float acc0 = 0.f, acc1 = 0.f, ss = 0.f;
    const unsigned int* xlp = xl32 + lane;
#pragma unroll 8
    for (int p = r0; p < r1; ++p) {
        int2 r = rec[p];
        __half2 hx = *(__half2*)&r.y;
        float2 e2 = __half22float2(hx);
        float ex = (lane < 32) ? e2.x : e2.y;
        unsigned int pr = xlp[(size_t)r.x * 64];
        ss += ex;
        acc0 += ex * bf2f((unsigned short)(pr & 0xFFFFu));
        acc1 += ex * bf2f((unsigned short)(pr >> 16));
    }
    float inv_s = 1.f / (ss + 1e-16f);
    acc0 *= inv_s; acc1 *= inv_s;
    float o0 = 0.5f * (acc0 + __shfl_xor(acc0, 32));
    float o1 = 0.5f * (acc1 + __shfl_xor(acc1, 32));
    if (lane < 32) {
        float2 hv = ((const float2*)(hprev + (size_t)n * 64))[lane];
        float2 sc = ((const float2*)scsh)[lane];
        float2 sf = ((const float2*)(scsh + 64))[lane];
        hv.x = fmaxf(hv.x * sc.x + sf.x, 0.f);
        hv.y = fmaxf(hv.y * sc.y + sf.y, 0.f);
        float2 bv = ((const float2*)bias)[lane];
        float2 o;
        o.x = o0 + bv.x + hv.x;
        o.y = o1 + bv.y + hv.y;
        ((float2*)(out + (size_t)n * 64))[lane] = o;
    }
}

extern "C" void kernel_launch(void* const* d_in, const int* in_sizes, int n_in,
                              void* d_out, int out_size, void* d_ws, size_t ws_size,
                              hipStream_t stream) {
    (void)in_sizes; (void)n_in; (void)out_size; (void)ws_size;
    const float* x     = (const float*)d_in[0];
    const int*   eidx  = (const int*)d_in[1];
    const float* eattr = (const float*)d_in[2];
    const float* instr = (const float*)d_in[3];
    const int*   batch = (const int*)d_in[4];
    const float* W_l   = (const float*)d_in[5];
    const float* W_e   = (const float*)d_in[6];
    const float* att_l = (const float*)d_in[7];
    const float* att_r = (const float*)d_in[8];
    const float* att_e = (const float*)d_in[9];
    const float* bias  = (const float*)d_in[10];
    const float* bn_g  = (const float*)d_in[11];
    const float* bn_b  = (const float*)d_in[12];
    float* out = (float*)d_out;

    const int* src = eidx;
    const int* dst = eidx + NE;

    char* ws = (char*)d_ws;
    int4*   einfo   = (int4*)ws;       ws += (size_t)NE * 16;
    int2*   rec1    = (int2*)ws;       ws += (size_t)NE * 8;
    unsigned short* xlh = (unsigned short*)ws; ws += (size_t)NN * 128 * 2;
    int*    deg     = (int*)ws;        ws += NN * 4;                 // |-- zeroed as one
    float*  part    = (float*)ws;      ws += PBKT * 128 * 4;         // |   contiguous memset region
    int*    rowptr  = (int*)ws;        ws += (NN + 1) * 4 + 12;
    int*    cursor  = (int*)ws;        ws += NN * 4;
    int*    bsum    = (int*)ws;        ws += 80 * 4;
    int*    boff    = (int*)ws;        ws += 80 * 4;
    float*  alc     = (float*)ws;      ws += NN * 2 * 4;
    float*  ar      = (float*)ws;      ws += NN * 2 * 4;
    float*  insl01  = (float*)ws;      ws += 2 * 128 * 128 * 4;
    float*  veT     = (float*)ws;      ws += 64 * 16;                // 64 x float4, transposed ve
    float*  ce01    = (float*)ws;      ws += 2 * 256 * 4;
    float*  hbuf    = (float*)ws;      ws += (size_t)NN * 64 * 4;
    float*  scsh    = (float*)ws;      ws += 128 * 4;

    hipMemsetAsync(deg, 0, NN * 4 + PBKT * 128 * 4, stream);

    // 1: hist + insl + veT/ce precompute
    k_front<<<1380, 256, 0, stream>>>(dst, deg, instr, W_l, W_e, att_e, insl01, veT, ce01);
    // 2-4: CSR rowptr/cursor (proven parallel chain)
    k_scanA<<<NBLK, 256, 0, stream>>>(deg, bsum);
    k_scanB<<<1, 64, 0, stream>>>(bsum, boff, rowptr);
    k_scanC<<<NBLK, 256, 0, stream>>>(deg, boff, rowptr, cursor);
    // 5: layer-0 node linear
    k_node<<<(NN + 7) / 8, 256, 0, stream>>>(x, W_l, insl01, batch,
                                             att_l, att_r, (const float2*)ce01,
                                             scsh, 0, xlh, alc, ar);
    // 6: edge dots (both layers) + L0 logits; half-tile staging + scalar veT
    k_sced<<<NE / 64, 64, 0, stream>>>(src, dst, eattr, (const float4*)veT,
                                       (const float2*)alc, (const float2*)ar, cursor, einfo);
    // 7: layer-0 gather + fence-free BN partial atomics
    k_gather0<<<NN / 4, 256, 0, stream>>>(rowptr, (const int2*)einfo + 1,
                                          (const unsigned int*)xlh, bias, x, hbuf, part);
    // 8: BN finalize -> scsh
    k_bnfin<<<1, 512, 0, stream>>>(part, bn_g, bn_b, scsh);
    // 9: layer-1 node linear (fused BN+relu on input)
    k_node<<<(NN + 7) / 8, 256, 0, stream>>>(hbuf, W_l + 128 * 128, insl01 + 16384, batch,
                                             att_l + 128, att_r + 128, (const float2*)(ce01 + 256),
                                             scsh, 1, xlh, alc, ar);
    // 10: layer-1 logits+exp, CSR-coalesced
    k_attnexp<<<(NE + 255) / 256, 256, 0, stream>>>(einfo, (const float2*)alc, (const float2*)ar, rec1);
    // 11: layer-1 gather, dense rec
    k_gather1<<<NN / 4, 256, 0, stream>>>(rowptr, rec1, (const unsigned int*)xlh,
                                          bias + 64, hbuf, scsh, out);
}

// Round 8
// 292.512 us; speedup vs baseline: 1.2161x; 1.2161x over previous
//
#include <hip/hip_runtime.h>
#include <hip/hip_fp16.h>
#include <math.h>

#define NN 20000
#define NE 320000
#define NB 128
#define SLOPE 0.2f
#define BN_EPS 1e-5f
#define NBLK 79   // ceil(NN/256)
#define PBKT 256  // BN partial bucket rows
#define ROWS_H 33 // half-tile LDS row stride (floats): (el+k)%32 -> 2-way, free

__device__ __forceinline__ unsigned short f2bf(float f) {
    unsigned int u = __float_as_uint(f);
    unsigned int r = (u + 0x7FFFu + ((u >> 16) & 1u)) >> 16;
    return (unsigned short)r;
}
__device__ __forceinline__ float bf2f(unsigned short h) {
    return __uint_as_float(((unsigned int)h) << 16);
}

// ---------- fused front: hist (0..1249) + insl (1250..1377) + ve/ce (1378..1379) ----------
// ve written TRANSPOSED into veT[64] float4: veT[k] = {L0h0, L0h1, L1h0, L1h1}[k]
__global__ __launch_bounds__(256) void k_front(const int* __restrict__ dst, int* __restrict__ deg,
                                               const float* __restrict__ instr, const float* __restrict__ Wl,
                                               const float* __restrict__ We, const float* __restrict__ atte,
                                               float* __restrict__ insl01, float* __restrict__ veTf,
                                               float* __restrict__ ce01) {
    __shared__ float w2[128];
    int blk = blockIdx.x, t = threadIdx.x;
    if (blk < 1250) {
        int e = blk * 256 + t;
        atomicAdd(&deg[dst[e]], 1);
    } else if (blk < 1378) {
        int bb = blk - 1250;
        int L = bb >> 6;
        int idx = (bb & 63) * 256 + t;
        int b = idx >> 7, j = idx & 127;
        const float* ins = instr + (size_t)L * NB * 64;
        const float* WlL = Wl + (size_t)L * 128 * 128;
        float acc = 0.f;
        for (int k = 0; k < 64; ++k) acc += ins[b * 64 + k] * WlL[(64 + k) * 128 + j];
        insl01[(size_t)L * 16384 + idx] = acc;
    } else {
        int L = blk - 1378;
        const float* WeL = We + (size_t)L * 128 * 128;
        const float* aeL = atte + L * 128;
        int h = (t >> 6) & 1;
        int k = t & 63;
        int row = (t < 128) ? k : (64 + k);
        float acc = 0.f;
        for (int c = 0; c < 64; ++c) acc += WeL[row * 128 + h * 64 + c] * aeL[h * 64 + c];
        if (t < 128) veTf[k * 4 + L * 2 + h] = acc;   // transposed packing for sced scalar loads
        else        w2[t - 128] = acc;
        __syncthreads();
        int b = t >> 1, hh = t & 1;
        const float* ins = instr + (size_t)L * NB * 64;
        float a2 = 0.f;
        for (int kk = 0; kk < 64; ++kk) a2 += ins[b * 64 + kk] * w2[hh * 64 + kk];
        ce01[L * 256 + b * 2 + hh] = a2;
    }
}

// ---------- CSR scan (proven 3-kernel chain, round-0 verbatim) ----------
__global__ __launch_bounds__(256) void k_scanA(const int* __restrict__ deg, int* __restrict__ bsum) {
    __shared__ int wsum[4];
    int t = threadIdx.x;
    int idx = blockIdx.x * 256 + t;
    int v = (idx < NN) ? deg[idx] : 0;
    for (int off = 32; off > 0; off >>= 1) v += __shfl_xor(v, off);
    if ((t & 63) == 0) wsum[t >> 6] = v;
    __syncthreads();
    if (t == 0) bsum[blockIdx.x] = wsum[0] + wsum[1] + wsum[2] + wsum[3];
}

__global__ __launch_bounds__(64) void k_scanB(const int* __restrict__ bsum, int* __restrict__ boff,
                                              int* __restrict__ rowptr) {
    int l = threadIdx.x;
    int v0 = (l < NBLK) ? bsum[l] : 0;
    int v1 = (64 + l < NBLK) ? bsum[64 + l] : 0;
    int o0 = v0, o1 = v1;
    for (int off = 1; off < 64; off <<= 1) { int u = __shfl_up(v0, off); if (l >= off) v0 += u; }
    int tot0 = __shfl(v0, 63);
    for (int off = 1; off < 64; off <<= 1) { int u = __shfl_up(v1, off); if (l >= off) v1 += u; }
    int tot1 = __shfl(v1, 63);
    if (l < NBLK) boff[l] = v0 - o0;
    if (64 + l < NBLK) boff[64 + l] = tot0 + v1 - o1;
    if (l == 0) rowptr[NN] = tot0 + tot1;
}

__global__ __launch_bounds__(256) void k_scanC(const int* __restrict__ deg, const int* __restrict__ boff,
                                               int* __restrict__ rowptr, int* __restrict__ cursor) {
    __shared__ int wsum[4];
    int t = threadIdx.x, lane = t & 63, w = t >> 6;
    int idx = blockIdx.x * 256 + t;
    int v = (idx < NN) ? deg[idx] : 0;
    int incl = v;
    for (int off = 1; off < 64; off <<= 1) { int u = __shfl_up(incl, off); if (lane >= off) incl += u; }
    if (lane == 63) wsum[w] = incl;
    __syncthreads();
    int pre = 0;
    for (int i = 0; i < w; ++i) pre += wsum[i];
    int excl = incl - v + pre + boff[blockIdx.x];
    if (idx < NN) { rowptr[idx] = excl; cursor[idx] = excl; }
}

// ---------- node linear (round-5 proven): xl (bf16) + alc + ar; optional fused BN+relu ----------
__global__ __launch_bounds__(256) void k_node(const float* __restrict__ hcur, const float* __restrict__ Wl,
                                              const float* __restrict__ insl, const int* __restrict__ batch,
                                              const float* __restrict__ attl, const float* __restrict__ attr_,
                                              const float2* __restrict__ ce2,
                                              const float* __restrict__ scsh, int use_bn,
                                              unsigned short* __restrict__ xlh,
                                              float* __restrict__ alc, float* __restrict__ ar) {
    __shared__ float sh[8 * 64];
    int t = threadIdx.x;
    int row0 = blockIdx.x * 8;
    for (int idx = t; idx < 512; idx += 256) {
        int r = idx >> 6, k = idx & 63;
        int n = row0 + r;
        float hv = (n < NN) ? hcur[n * 64 + k] : 0.f;
        if (use_bn) hv = fmaxf(hv * scsh[k] + scsh[64 + k], 0.f);
        sh[idx] = hv;
    }
    __syncthreads();
    int w = t >> 6, lane = t & 63;
    int h = w & 1;
    int rbase = (w >> 1) * 4;
    int j = h * 64 + lane;
    float attlv = attl[j];
    float attrv = attr_[j];
    float acc0 = 0.f, acc1 = 0.f, acc2 = 0.f, acc3 = 0.f;
    for (int k = 0; k < 64; ++k) {
        float wv = Wl[k * 128 + j];
        acc0 += sh[(rbase + 0) * 64 + k] * wv;
        acc1 += sh[(rbase + 1) * 64 + k] * wv;
        acc2 += sh[(rbase + 2) * 64 + k] * wv;
        acc3 += sh[(rbase + 3) * 64 + k] * wv;
    }
    float accs[4] = {acc0, acc1, acc2, acc3};
    for (int rr = 0; rr < 4; ++rr) {
        int n = row0 + rbase + rr;
        if (n >= NN) break;
        int b = batch[n];
        float v = accs[rr] + insl[b * 128 + j];
        xlh[(size_t)n * 128 + j] = f2bf(v);
        float pl = v * attlv, pr = v * attrv;
        for (int off = 32; off > 0; off >>= 1) {
            pl += __shfl_xor(pl, off);
            pr += __shfl_xor(pr, off);
        }
        if (lane == 0) {
            float2 cb = ce2[b];
            alc[n * 2 + h] = pl + (h ? cb.y : cb.x);
            ar[n * 2 + h] = pr;
        }
    }
}

// ---------- edge kernel v6: half-tile LDS staging + veT via wave-uniform (scalar) loads ----------
__global__ __launch_bounds__(64) void k_sced(const int* __restrict__ src, const int* __restrict__ dst,
                                             const float* __restrict__ eattr, const float4* __restrict__ veT,
                                             const float2* __restrict__ alc2, const float2* __restrict__ ar2,
                                             int* __restrict__ cursor, int4* __restrict__ einfo) {
    __shared__ float se[64 * ROWS_H];   // 8448 B
    int lane = threadIdx.x;
    int ebase = blockIdx.x * 64;
    float d0 = 0.f, d1 = 0.f, d2 = 0.f, d3 = 0.f;
    const float* row = se + lane * ROWS_H;
#pragma unroll
    for (int half = 0; half < 2; ++half) {
        const float4* gsrc = (const float4*)eattr + (size_t)ebase * 16 + half * 8;
#pragma unroll
        for (int i = 0; i < 8; ++i) {
            int fi = i * 64 + lane;
            int el = fi >> 3, q = fi & 7;
            float4 f = gsrc[(size_t)el * 16 + q];
            float* dp = se + el * ROWS_H + q * 4;
            dp[0] = f.x; dp[1] = f.y; dp[2] = f.z; dp[3] = f.w;
        }
        // veT index is wave-uniform -> scalar-cache loads, LDS pipe freed
#pragma unroll
        for (int k = 0; k < 32; ++k) {
            float fv = row[k];
            float4 vt = veT[half * 32 + k];
            d0 += fv * vt.x; d1 += fv * vt.y; d2 += fv * vt.z; d3 += fv * vt.w;
        }
    }
    int e = ebase + lane;
    int s = src[e], dd = dst[e];
    float2 al = alc2[s], arr = ar2[dd];
    float a0 = al.x + arr.x + d0;
    float a1 = al.y + arr.y + d1;
    a0 = (a0 > 0.f) ? a0 : SLOPE * a0;
    a1 = (a1 > 0.f) ? a1 : SLOPE * a1;
    __half2 ex = __floats2half2_rn(__expf(a0), __expf(a1));
    __half2 d23 = __floats2half2_rn(d2, d3);
    int pos = atomicAdd(&cursor[dd], 1);
    einfo[pos] = make_int4(s | (dd << 15), *(int*)&d23, s, *(int*)&ex);
}

// ---------- layer-0 gather: weighted mean + bias + residual; BN partials via fence-free atomics ----------
__global__ __launch_bounds__(256) void k_gather0(const int* __restrict__ rowptr, const int2* __restrict__ rec,
                                                 const unsigned int* __restrict__ xl32,
                                                 const float* __restrict__ bias, const float* __restrict__ hprev,
                                                 float* __restrict__ hnew, float* __restrict__ part) {
    __shared__ float smv[4][64];
    __shared__ float smq[4][64];
    int t = threadIdx.x;
    int w = t >> 6, lane = t & 63;
    int n = blockIdx.x * 4 + w;
    int r0 = rowptr[n], r1 = rowptr[n + 1];
    float acc0 = 0.f, acc1 = 0.f, ss = 0.f;
    const unsigned int* xlp = xl32 + lane;
#pragma unroll 8
    for (int p = r0; p < r1; ++p) {
        int2 r = rec[(size_t)p * 2];
        __half2 hx = *(__half2*)&r.y;
        float2 e2 = __half22float2(hx);
        float ex = (lane < 32) ? e2.x : e2.y;
        unsigned int pr = xlp[(size_t)r.x * 64];
        ss += ex;
        acc0 += ex * bf2f((unsigned short)(pr & 0xFFFFu));
        acc1 += ex * bf2f((unsigned short)(pr >> 16));
    }
    float inv_s = 1.f / (ss + 1e-16f);
    acc0 *= inv_s; acc1 *= inv_s;
    float o0 = 0.5f * (acc0 + __shfl_xor(acc0, 32));
    float o1 = 0.5f * (acc1 + __shfl_xor(acc1, 32));
    if (lane < 32) {
        float2 hv = ((const float2*)(hprev + (size_t)n * 64))[lane];
        float2 bv = ((const float2*)bias)[lane];
        float2 o;
        o.x = o0 + bv.x + hv.x;
        o.y = o1 + bv.y + hv.y;
        ((float2*)(hnew + (size_t)n * 64))[lane] = o;
        smv[w][2 * lane]     = o.x;
        smv[w][2 * lane + 1] = o.y;
        smq[w][2 * lane]     = o.x * o.x;
        smq[w][2 * lane + 1] = o.y * o.y;
    }
    __syncthreads();
    if (t < 128) {
        int c = t & 63, which = t >> 6;
        float a = which ? (smq[0][c] + smq[1][c] + smq[2][c] + smq[3][c])
                        : (smv[0][c] + smv[1][c] + smv[2][c] + smv[3][c]);
        atomicAdd(&part[(blockIdx.x & (PBKT - 1)) * 128 + which * 64 + c], a);
    }
}

// ---------- BN finalize: reduce PBKT x 128 partials -> scsh ----------
__global__ __launch_bounds__(512) void k_bnfin(const float* __restrict__ part,
                                               const float* __restrict__ gamma, const float* __restrict__ beta,
                                               float* __restrict__ scsh) {
    __shared__ float red[512];
    __shared__ float tot[128];
    int t = threadIdx.x;
    int col = t & 127, q = t >> 7;
    float s = 0.f;
    for (int r = q * (PBKT / 4); r < (q + 1) * (PBKT / 4); ++r) s += part[r * 128 + col];
    red[t] = s;
    __syncthreads();
    if (t < 128) tot[t] = red[t] + red[t + 128] + red[t + 256] + red[t + 384];
    __syncthreads();
    if (t < 64) {
        float su = tot[t];
        float sq = tot[64 + t];
        float mu = su * (1.f / NN);
        float var = sq * (1.f / NN) - mu * mu;
        float sc = gamma[t] * rsqrtf(var + BN_EPS);
        scsh[t] = sc;
        scsh[64 + t] = beta[t] - mu * sc;
    }
}

// ---------- layer-1 logits + exp (CSR order, coalesced read/write) ----------
__global__ __launch_bounds__(256) void k_attnexp(const int4* __restrict__ einfo,
                                                 const float2* __restrict__ alc2, const float2* __restrict__ ar2,
                                                 int2* __restrict__ rec1) {
    int p = blockIdx.x * 256 + threadIdx.x;
    if (p >= NE) return;
    int4 r = einfo[p];
    int s = r.x & 0x7FFF, d = r.x >> 15;
    __half2 hd = *(__half2*)&r.y;
    float2 dv = __half22float2(hd);
    float2 a_l = alc2[s];
    float2 a_r = ar2[d];
    float a0 = a_l.x + a_r.x + dv.x;
    float a1 = a_l.y + a_r.y + dv.y;
    a0 = (a0 > 0.f) ? a0 : SLOPE * a0;
    a1 = (a1 > 0.f) ? a1 : SLOPE * a1;
    __half2 hx = __floats2half2_rn(__expf(a0), __expf(a1));
    rec1[p] = make_int2(s, *(int*)&hx);
}

// ---------- layer-1 gather: dense 8B rec; BN'd residual ----------
__global__ __launch_bounds__(256) void k_gather1(const int* __restrict__ rowptr, const int2* __restrict__ rec,
                                                 const unsigned int* __restrict__ xl32,
                                                 const float* __restrict__ bias, const float* __restrict__ hprev,
                                                 const float* __restrict__ scsh, float* __restrict__ out) {
    int t = threadIdx.x;
    int w = t >> 6, lane = t & 63;
    int n = blockIdx.x * 4 + w;
    int r0 = rowptr[n], r1 = rowptr[n + 1];
    float acc0 = 0.f, acc1 = 0.f, ss = 0.f;
    const unsigned int* xlp = xl32 + lane;
#pragma unroll 8
    for (int p = r0; p < r1; ++p) {
        int2 r = rec[p];
        __half2 hx = *(__half2*)&r.y;
        float2 e2 = __half22float2(hx);
        float ex = (lane < 32) ? e2.x : e2.y;
        unsigned int pr = xlp[(size_t)r.x * 64];
        ss += ex;
        acc0 += ex * bf2f((unsigned short)(pr & 0xFFFFu));
        acc1 += ex * bf2f((unsigned short)(pr >> 16));
    }
    float inv_s = 1.f / (ss + 1e-16f);
    acc0 *= inv_s; acc1 *= inv_s;
    float o0 = 0.5f * (acc0 + __shfl_xor(acc0, 32));
    float o1 = 0.5f * (acc1 + __shfl_xor(acc1, 32));
    if (lane < 32) {
        float2 hv = ((const float2*)(hprev + (size_t)n * 64))[lane];
        float2 sc = ((const float2*)scsh)[lane];
        float2 sf = ((const float2*)(scsh + 64))[lane];
        hv.x = fmaxf(hv.x * sc.x + sf.x, 0.f);
        hv.y = fmaxf(hv.y * sc.y + sf.y, 0.f);
        float2 bv = ((const float2*)bias)[lane];
        float2 o;
        o.x = o0 + bv.x + hv.x;
        o.y = o1 + bv.y + hv.y;
        ((float2*)(out + (size_t)n * 64))[lane] = o;
    }
}

extern "C" void kernel_launch(void* const* d_in, const int* in_sizes, int n_in,
                              void* d_out, int out_size, void* d_ws, size_t ws_size,
                              hipStream_t stream) {
    (void)in_sizes; (void)n_in; (void)out_size; (void)ws_size;
    const float* x     = (const float*)d_in[0];
    const int*   eidx  = (const int*)d_in[1];
    const float* eattr = (const float*)d_in[2];
    const float* instr = (const float*)d_in[3];
    const int*   batch = (const int*)d_in[4];
    const float* W_l   = (const float*)d_in[5];
    const float* W_e   = (const float*)d_in[6];
    const float* att_l = (const float*)d_in[7];
    const float* att_r = (const float*)d_in[8];
    const float* att_e = (const float*)d_in[9];
    const float* bias  = (const float*)d_in[10];
    const float* bn_g  = (const float*)d_in[11];
    const float* bn_b  = (const float*)d_in[12];
    float* out = (float*)d_out;

    const int* src = eidx;
    const int* dst = eidx + NE;

    char* ws = (char*)d_ws;
    int4*   einfo   = (int4*)ws;       ws += (size_t)NE * 16;
    int2*   rec1    = (int2*)ws;       ws += (size_t)NE * 8;
    unsigned short* xlh = (unsigned short*)ws; ws += (size_t)NN * 128 * 2;
    int*    deg     = (int*)ws;        ws += NN * 4;                 // |-- zeroed as one
    float*  part    = (float*)ws;      ws += PBKT * 128 * 4;         // |   contiguous memset region
    int*    rowptr  = (int*)ws;        ws += (NN + 1) * 4 + 12;
    int*    cursor  = (int*)ws;        ws += NN * 4;
    int*    bsum    = (int*)ws;        ws += 80 * 4;
    int*    boff    = (int*)ws;        ws += 80 * 4;
    float*  alc     = (float*)ws;      ws += NN * 2 * 4;
    float*  ar      = (float*)ws;      ws += NN * 2 * 4;
    float*  insl01  = (float*)ws;      ws += 2 * 128 * 128 * 4;
    float*  veT     = (float*)ws;      ws += 64 * 16;                // 64 x float4, transposed ve
    float*  ce01    = (float*)ws;      ws += 2 * 256 * 4;
    float*  hbuf    = (float*)ws;      ws += (size_t)NN * 64 * 4;
    float*  scsh    = (float*)ws;      ws += 128 * 4;

    hipMemsetAsync(deg, 0, NN * 4 + PBKT * 128 * 4, stream);

    // 1: hist + insl + veT/ce precompute
    k_front<<<1380, 256, 0, stream>>>(dst, deg, instr, W_l, W_e, att_e, insl01, veT, ce01);
    // 2-4: CSR rowptr/cursor (proven parallel chain)
    k_scanA<<<NBLK, 256, 0, stream>>>(deg, bsum);
    k_scanB<<<1, 64, 0, stream>>>(bsum, boff, rowptr);
    k_scanC<<<NBLK, 256, 0, stream>>>(deg, boff, rowptr, cursor);
    // 5: layer-0 node linear
    k_node<<<(NN + 7) / 8, 256, 0, stream>>>(x, W_l, insl01, batch,
                                             att_l, att_r, (const float2*)ce01,
                                             scsh, 0, xlh, alc, ar);
    // 6: edge dots (both layers) + L0 logits; half-tile staging + scalar veT
    k_sced<<<NE / 64, 64, 0, stream>>>(src, dst, eattr, (const float4*)veT,
                                       (const float2*)alc, (const float2*)ar, cursor, einfo);
    // 7: layer-0 gather + fence-free BN partial atomics
    k_gather0<<<NN / 4, 256, 0, stream>>>(rowptr, (const int2*)einfo + 1,
                                          (const unsigned int*)xlh, bias, x, hbuf, part);
    // 8: BN finalize -> scsh
    k_bnfin<<<1, 512, 0, stream>>>(part, bn_g, bn_b, scsh);
    // 9: layer-1 node linear (fused BN+relu on input)
    k_node<<<(NN + 7) / 8, 256, 0, stream>>>(hbuf, W_l + 128 * 128, insl01 + 16384, batch,
                                             att_l + 128, att_r + 128, (const float2*)(ce01 + 256),
                                             scsh, 1, xlh, alc, ar);
    // 10: layer-1 logits+exp, CSR-coalesced
    k_attnexp<<<(NE + 255) / 256, 256, 0, stream>>>(einfo, (const float2*)alc, (const float2*)ar, rec1);
    // 11: layer-1 gather, dense rec
    k_gather1<<<NN / 4, 256, 0, stream>>>(rowptr, rec1, (const unsigned int*)xlh,
                                          bias + 64, hbuf, scsh, out);
}

// Round 9
// 287.052 us; speedup vs baseline: 1.2392x; 1.0190x over previous
//
#include <hip/hip_runtime.h>
#include <hip/hip_fp16.h>
#include <math.h>

#define NN 20000
#define NE 320000
#define NB 128
#define SLOPE 0.2f
#define BN_EPS 1e-5f
#define NBLK 79   // ceil(NN/256)
#define PBKT 256  // BN partial bucket rows
#define ROWS_H 33 // half-tile LDS row stride (floats): (el+k)%32 -> 2-way, free (odd stride is load-bearing)

__device__ __forceinline__ unsigned short f2bf(float f) {
    unsigned int u = __float_as_uint(f);
    unsigned int r = (u + 0x7FFFu + ((u >> 16) & 1u)) >> 16;
    return (unsigned short)r;
}
__device__ __forceinline__ float bf2f(unsigned short h) {
    return __uint_as_float(((unsigned int)h) << 16);
}

// ---------- fused front: hist (0..1249) + insl (1250..1377) + ve/ce (1378..1379) ----------
__global__ __launch_bounds__(256) void k_front(const int* __restrict__ dst, int* __restrict__ deg,
                                               const float* __restrict__ instr, const float* __restrict__ Wl,
                                               const float* __restrict__ We, const float* __restrict__ atte,
                                               float* __restrict__ insl01, float* __restrict__ ve01,
                                               float* __restrict__ ce01) {
    __shared__ float w2[128];
    int blk = blockIdx.x, t = threadIdx.x;
    if (blk < 1250) {
        int e = blk * 256 + t;
        atomicAdd(&deg[dst[e]], 1);
    } else if (blk < 1378) {
        int bb = blk - 1250;
        int L = bb >> 6;
        int idx = (bb & 63) * 256 + t;
        int b = idx >> 7, j = idx & 127;
        const float* ins = instr + (size_t)L * NB * 64;
        const float* WlL = Wl + (size_t)L * 128 * 128;
        float acc = 0.f;
        for (int k = 0; k < 64; ++k) acc += ins[b * 64 + k] * WlL[(64 + k) * 128 + j];
        insl01[(size_t)L * 16384 + idx] = acc;
    } else {
        int L = blk - 1378;
        const float* WeL = We + (size_t)L * 128 * 128;
        const float* aeL = atte + L * 128;
        int h = (t >> 6) & 1;
        int k = t & 63;
        int row = (t < 128) ? k : (64 + k);
        float acc = 0.f;
        for (int c = 0; c < 64; ++c) acc += WeL[row * 128 + h * 64 + c] * aeL[h * 64 + c];
        if (t < 128) ve01[L * 128 + t] = acc;
        else        w2[t - 128] = acc;
        __syncthreads();
        int b = t >> 1, hh = t & 1;
        const float* ins = instr + (size_t)L * NB * 64;
        float a2 = 0.f;
        for (int kk = 0; kk < 64; ++kk) a2 += ins[b * 64 + kk] * w2[hh * 64 + kk];
        ce01[L * 256 + b * 2 + hh] = a2;
    }
}

// ---------- CSR scan: 2-kernel chain (scanB folded into scanC via masked wave-reduce) ----------
__global__ __launch_bounds__(256) void k_scanA(const int* __restrict__ deg, int* __restrict__ bsum) {
    __shared__ int wsum[4];
    int t = threadIdx.x;
    int idx = blockIdx.x * 256 + t;
    int v = (idx < NN) ? deg[idx] : 0;
    for (int off = 32; off > 0; off >>= 1) v += __shfl_xor(v, off);
    if ((t & 63) == 0) wsum[t >> 6] = v;
    __syncthreads();
    if (t == 0) bsum[blockIdx.x] = wsum[0] + wsum[1] + wsum[2] + wsum[3];
}

__global__ __launch_bounds__(256) void k_scanC(const int* __restrict__ deg, const int* __restrict__ bsum,
                                               int* __restrict__ rowptr, int* __restrict__ cursor) {
    __shared__ int wsum[4];
    __shared__ int sboff;
    int t = threadIdx.x, lane = t & 63, w = t >> 6;
    int blk = blockIdx.x;
    if (t < 64) {   // wave-uniform branch: wave 0 computes this block's global offset
        int b0 = (lane < NBLK) ? bsum[lane] : 0;
        int b1 = (64 + lane < NBLK) ? bsum[64 + lane] : 0;
        int m = ((lane < blk) ? b0 : 0) + ((64 + lane < blk) ? b1 : 0);
        for (int off = 32; off > 0; off >>= 1) m += __shfl_xor(m, off);
        if (lane == 0) sboff = m;
        if (blk == 0) {
            int tt = b0 + b1;
            for (int off = 32; off > 0; off >>= 1) tt += __shfl_xor(tt, off);
            if (lane == 0) rowptr[NN] = tt;
        }
    }
    int idx = blk * 256 + t;
    int v = (idx < NN) ? deg[idx] : 0;
    int incl = v;
    for (int off = 1; off < 64; off <<= 1) { int u = __shfl_up(incl, off); if (lane >= off) incl += u; }
    if (lane == 63) wsum[w] = incl;
    __syncthreads();
    int pre = 0;
    for (int i = 0; i < w; ++i) pre += wsum[i];
    int excl = incl - v + pre + sboff;
    if (idx < NN) { rowptr[idx] = excl; cursor[idx] = excl; }
}

// ---------- node linear (round-5 proven): xl (bf16) + alc + ar; optional fused BN+relu ----------
__global__ __launch_bounds__(256) void k_node(const float* __restrict__ hcur, const float* __restrict__ Wl,
                                              const float* __restrict__ insl, const int* __restrict__ batch,
                                              const float* __restrict__ attl, const float* __restrict__ attr_,
                                              const float2* __restrict__ ce2,
                                              const float* __restrict__ scsh, int use_bn,
                                              unsigned short* __restrict__ xlh,
                                              float* __restrict__ alc, float* __restrict__ ar) {
    __shared__ float sh[8 * 64];
    int t = threadIdx.x;
    int row0 = blockIdx.x * 8;
    for (int idx = t; idx < 512; idx += 256) {
        int r = idx >> 6, k = idx & 63;
        int n = row0 + r;
        float hv = (n < NN) ? hcur[n * 64 + k] : 0.f;
        if (use_bn) hv = fmaxf(hv * scsh[k] + scsh[64 + k], 0.f);
        sh[idx] = hv;
    }
    __syncthreads();
    int w = t >> 6, lane = t & 63;
    int h = w & 1;
    int rbase = (w >> 1) * 4;
    int j = h * 64 + lane;
    float attlv = attl[j];
    float attrv = attr_[j];
    float acc0 = 0.f, acc1 = 0.f, acc2 = 0.f, acc3 = 0.f;
    for (int k = 0; k < 64; ++k) {
        float wv = Wl[k * 128 + j];
        acc0 += sh[(rbase + 0) * 64 + k] * wv;
        acc1 += sh[(rbase + 1) * 64 + k] * wv;
        acc2 += sh[(rbase + 2) * 64 + k] * wv;
        acc3 += sh[(rbase + 3) * 64 + k] * wv;
    }
    float accs[4] = {acc0, acc1, acc2, acc3};
    for (int rr = 0; rr < 4; ++rr) {
        int n = row0 + rbase + rr;
        if (n >= NN) break;
        int b = batch[n];
        float v = accs[rr] + insl[b * 128 + j];
        xlh[(size_t)n * 128 + j] = f2bf(v);
        float pl = v * attlv, pr = v * attrv;
        for (int off = 32; off > 0; off >>= 1) {
            pl += __shfl_xor(pl, off);
            pr += __shfl_xor(pr, off);
        }
        if (lane == 0) {
            float2 cb = ce2[b];
            alc[n * 2 + h] = pl + (h ? cb.y : cb.x);
            ar[n * 2 + h] = pr;
        }
    }
}

// ---------- edge kernel v5 (round-5 proven): half-tile LDS staging + in-kernel svT transpose ----------
__global__ __launch_bounds__(64) void k_sced(const int* __restrict__ src, const int* __restrict__ dst,
                                             const float* __restrict__ eattr, const float* __restrict__ ve01,
                                             const float2* __restrict__ alc2, const float2* __restrict__ ar2,
                                             int* __restrict__ cursor, int4* __restrict__ einfo) {
    __shared__ float se[64 * ROWS_H];   // 8448 B
    __shared__ float svT[256];          // 1 KB
    int lane = threadIdx.x;
#pragma unroll
    for (int i = 0; i < 4; ++i) {
        int idx = i * 64 + lane;
        svT[idx] = ve01[(idx & 3) * 64 + (idx >> 2)];   // svT[4k+j] = ve01[j*64+k]
    }
    int ebase = blockIdx.x * 64;
    float d0 = 0.f, d1 = 0.f, d2 = 0.f, d3 = 0.f;
    const float* row = se + lane * ROWS_H;
#pragma unroll
    for (int half = 0; half < 2; ++half) {
        const float4* gsrc = (const float4*)eattr + (size_t)ebase * 16 + half * 8;
#pragma unroll
        for (int i = 0; i < 8; ++i) {
            int fi = i * 64 + lane;
            int el = fi >> 3, q = fi & 7;
            float4 f = gsrc[(size_t)el * 16 + q];
            float* dp = se + el * ROWS_H + q * 4;
            dp[0] = f.x; dp[1] = f.y; dp[2] = f.z; dp[3] = f.w;
        }
        const float* vbase = svT + half * 128;
#pragma unroll
        for (int k = 0; k < 32; ++k) {
            float fv = row[k];
            float4 vt = *(const float4*)&vbase[4 * k];
            d0 += fv * vt.x; d1 += fv * vt.y; d2 += fv * vt.z; d3 += fv * vt.w;
        }
    }
    int e = ebase + lane;
    int s = src[e], dd = dst[e];
    float2 al = alc2[s], arr = ar2[dd];
    float a0 = al.x + arr.x + d0;
    float a1 = al.y + arr.y + d1;
    a0 = (a0 > 0.f) ? a0 : SLOPE * a0;
    a1 = (a1 > 0.f) ? a1 : SLOPE * a1;
    __half2 ex = __floats2half2_rn(__expf(a0), __expf(a1));
    __half2 d23 = __floats2half2_rn(d2, d3);
    int pos = atomicAdd(&cursor[dd], 1);
    einfo[pos] = make_int4(s | (dd << 15), *(int*)&d23, s, *(int*)&ex);
}

// ---------- layer-0 gather: weighted mean + bias + residual; BN partials via fence-free atomics ----------
__global__ __launch_bounds__(256) void k_gather0(const int* __restrict__ rowptr, const int2* __restrict__ rec,
                                                 const unsigned int* __restrict__ xl32,
                                                 const float* __restrict__ bias, const float* __restrict__ hprev,
                                                 float* __restrict__ hnew, float* __restrict__ part) {
    __shared__ float smv[4][64];
    __shared__ float smq[4][64];
    int t = threadIdx.x;
    int w = t >> 6, lane = t & 63;
    int n = blockIdx.x * 4 + w;
    int r0 = rowptr[n], r1 = rowptr[n + 1];
    float acc0 = 0.f, acc1 = 0.f, ss = 0.f;
    const unsigned int* xlp = xl32 + lane;
#pragma unroll 8
    for (int p = r0; p < r1; ++p) {
        int2 r = rec[(size_t)p * 2];
        __half2 hx = *(__half2*)&r.y;
        float2 e2 = __half22float2(hx);
        float ex = (lane < 32) ? e2.x : e2.y;
        unsigned int pr = xlp[(size_t)r.x * 64];
        ss += ex;
        acc0 += ex * bf2f((unsigned short)(pr & 0xFFFFu));
        acc1 += ex * bf2f((unsigned short)(pr >> 16));
    }
    float inv_s = 1.f / (ss + 1e-16f);
    acc0 *= inv_s; acc1 *= inv_s;
    float o0 = 0.5f * (acc0 + __shfl_xor(acc0, 32));
    float o1 = 0.5f * (acc1 + __shfl_xor(acc1, 32));
    if (lane < 32) {
        float2 hv = ((const float2*)(hprev + (size_t)n * 64))[lane];
        float2 bv = ((const float2*)bias)[lane];
        float2 o;
        o.x = o0 + bv.x + hv.x;
        o.y = o1 + bv.y + hv.y;
        ((float2*)(hnew + (size_t)n * 64))[lane] = o;
        smv[w][2 * lane]     = o.x;
        smv[w][2 * lane + 1] = o.y;
        smq[w][2 * lane]     = o.x * o.x;
        smq[w][2 * lane + 1] = o.y * o.y;
    }
    __syncthreads();
    if (t < 128) {
        int c = t & 63, which = t >> 6;
        float a = which ? (smq[0][c] + smq[1][c] + smq[2][c] + smq[3][c])
                        : (smv[0][c] + smv[1][c] + smv[2][c] + smv[3][c]);
        atomicAdd(&part[(blockIdx.x & (PBKT - 1)) * 128 + which * 64 + c], a);
    }
}

// ---------- BN finalize: reduce PBKT x 128 partials -> scsh ----------
__global__ __launch_bounds__(512) void k_bnfin(const float* __restrict__ part,
                                               const float* __restrict__ gamma, const float* __restrict__ beta,
                                               float* __restrict__ scsh) {
    __shared__ float red[512];
    __shared__ float tot[128];
    int t = threadIdx.x;
    int col = t & 127, q = t >> 7;
    float s = 0.f;
    for (int r = q * (PBKT / 4); r < (q + 1) * (PBKT / 4); ++r) s += part[r * 128 + col];
    red[t] = s;
    __syncthreads();
    if (t < 128) tot[t] = red[t] + red[t + 128] + red[t + 256] + red[t + 384];
    __syncthreads();
    if (t < 64) {
        float su = tot[t];
        float sq = tot[64 + t];
        float mu = su * (1.f / NN);
        float var = sq * (1.f / NN) - mu * mu;
        float sc = gamma[t] * rsqrtf(var + BN_EPS);
        scsh[t] = sc;
        scsh[64 + t] = beta[t] - mu * sc;
    }
}

// ---------- layer-1 logits + exp (CSR order, coalesced read/write) ----------
__global__ __launch_bounds__(256) void k_attnexp(const int4* __restrict__ einfo,
                                                 const float2* __restrict__ alc2, const float2* __restrict__ ar2,
                                                 int2* __restrict__ rec1) {
    int p = blockIdx.x * 256 + threadIdx.x;
    if (p >= NE) return;
    int4 r = einfo[p];
    int s = r.x & 0x7FFF, d = r.x >> 15;
    __half2 hd = *(__half2*)&r.y;
    float2 dv = __half22float2(hd);
    float2 a_l = alc2[s];
    float2 a_r = ar2[d];
    float a0 = a_l.x + a_r.x + dv.x;
    float a1 = a_l.y + a_r.y + dv.y;
    a0 = (a0 > 0.f) ? a0 : SLOPE * a0;
    a1 = (a1 > 0.f) ? a1 : SLOPE * a1;
    __half2 hx = __floats2half2_rn(__expf(a0), __expf(a1));
    rec1[p] = make_int2(s, *(int*)&hx);
}

// ---------- layer-1 gather: dense 8B rec; BN'd residual ----------
__global__ __launch_bounds__(256) void k_gather1(const int* __restrict__ rowptr, const int2* __restrict__ rec,
                                                 const unsigned int* __restrict__ xl32,
                                                 const float* __restrict__ bias, const float* __restrict__ hprev,
                                                 const float* __restrict__ scsh, float* __restrict__ out) {
    int t = threadIdx.x;
    int w = t >> 6, lane = t & 63;
    int n = blockIdx.x * 4 + w;
    int r0 = rowptr[n], r1 = rowptr[n + 1];
    float acc0 = 0.f, acc1 = 0.f, ss = 0.f;
    const unsigned int* xlp = xl32 + lane;
#pragma unroll 8
    for (int p = r0; p < r1; ++p) {
        int2 r = rec[p];
        __half2 hx = *(__half2*)&r.y;
        float2 e2 = __half22float2(hx);
        float ex = (lane < 32) ? e2.x : e2.y;
        unsigned int pr = xlp[(size_t)r.x * 64];
        ss += ex;
        acc0 += ex * bf2f((unsigned short)(pr & 0xFFFFu));
        acc1 += ex * bf2f((unsigned short)(pr >> 16));
    }
    float inv_s = 1.f / (ss + 1e-16f);
    acc0 *= inv_s; acc1 *= inv_s;
    float o0 = 0.5f * (acc0 + __shfl_xor(acc0, 32));
    float o1 = 0.5f * (acc1 + __shfl_xor(acc1, 32));
    if (lane < 32) {
        float2 hv = ((const float2*)(hprev + (size_t)n * 64))[lane];
        float2 sc = ((const float2*)scsh)[lane];
        float2 sf = ((const float2*)(scsh + 64))[lane];
        hv.x = fmaxf(hv.x * sc.x + sf.x, 0.f);
        hv.y = fmaxf(hv.y * sc.y + sf.y, 0.f);
        float2 bv = ((const float2*)bias)[lane];
        float2 o;
        o.x = o0 + bv.x + hv.x;
        o.y = o1 + bv.y + hv.y;
        ((float2*)(out + (size_t)n * 64))[lane] = o;
    }
}

extern "C" void kernel_launch(void* const* d_in, const int* in_sizes, int n_in,
                              void* d_out, int out_size, void* d_ws, size_t ws_size,
                              hipStream_t stream) {
    (void)in_sizes; (void)n_in; (void)out_size; (void)ws_size;
    const float* x     = (const float*)d_in[0];
    const int*   eidx  = (const int*)d_in[1];
    const float* eattr = (const float*)d_in[2];
    const float* instr = (const float*)d_in[3];
    const int*   batch = (const int*)d_in[4];
    const float* W_l   = (const float*)d_in[5];
    const float* W_e   = (const float*)d_in[6];
    const float* att_l = (const float*)d_in[7];
    const float* att_r = (const float*)d_in[8];
    const float* att_e = (const float*)d_in[9];
    const float* bias  = (const float*)d_in[10];
    const float* bn_g  = (const float*)d_in[11];
    const float* bn_b  = (const float*)d_in[12];
    float* out = (float*)d_out;

    const int* src = eidx;
    const int* dst = eidx + NE;

    char* ws = (char*)d_ws;
    int4*   einfo   = (int4*)ws;       ws += (size_t)NE * 16;
    int2*   rec1    = (int2*)ws;       ws += (size_t)NE * 8;
    unsigned short* xlh = (unsigned short*)ws; ws += (size_t)NN * 128 * 2;
    int*    deg     = (int*)ws;        ws += NN * 4;                 // |-- zeroed as one
    float*  part    = (float*)ws;      ws += PBKT * 128 * 4;         // |   contiguous memset region
    int*    rowptr  = (int*)ws;        ws += (NN + 1) * 4 + 12;
    int*    cursor  = (int*)ws;        ws += NN * 4;
    int*    bsum    = (int*)ws;        ws += 80 * 4;
    float*  alc     = (float*)ws;      ws += NN * 2 * 4;
    float*  ar      = (float*)ws;      ws += NN * 2 * 4;
    float*  insl01  = (float*)ws;      ws += 2 * 128 * 128 * 4;
    float*  ve01    = (float*)ws;      ws += 256 * 4;
    float*  ce01    = (float*)ws;      ws += 2 * 256 * 4;
    float*  hbuf    = (float*)ws;      ws += (size_t)NN * 64 * 4;
    float*  scsh    = (float*)ws;      ws += 128 * 4;

    hipMemsetAsync(deg, 0, NN * 4 + PBKT * 128 * 4, stream);

    // 1: hist + insl + ve/ce precompute
    k_front<<<1380, 256, 0, stream>>>(dst, deg, instr, W_l, W_e, att_e, insl01, ve01, ce01);
    // 2-3: CSR rowptr/cursor (scanB folded into scanC)
    k_scanA<<<NBLK, 256, 0, stream>>>(deg, bsum);
    k_scanC<<<NBLK, 256, 0, stream>>>(deg, bsum, rowptr, cursor);
    // 4: layer-0 node linear
    k_node<<<(NN + 7) / 8, 256, 0, stream>>>(x, W_l, insl01, batch,
                                             att_l, att_r, (const float2*)ce01,
                                             scsh, 0, xlh, alc, ar);
    // 5: edge dots (both layers) + L0 logits; half-tile staging
    k_sced<<<NE / 64, 64, 0, stream>>>(src, dst, eattr, ve01,
                                       (const float2*)alc, (const float2*)ar, cursor, einfo);
    // 6: layer-0 gather + fence-free BN partial atomics
    k_gather0<<<NN / 4, 256, 0, stream>>>(rowptr, (const int2*)einfo + 1,
                                          (const unsigned int*)xlh, bias, x, hbuf, part);
    // 7: BN finalize -> scsh
    k_bnfin<<<1, 512, 0, stream>>>(part, bn_g, bn_b, scsh);
    // 8: layer-1 node linear (fused BN+relu on input)
    k_node<<<(NN + 7) / 8, 256, 0, stream>>>(hbuf, W_l + 128 * 128, insl01 + 16384, batch,
                                             att_l + 128, att_r + 128, (const float2*)(ce01 + 256),
                                             scsh, 1, xlh, alc, ar);
    // 9: layer-1 logits+exp, CSR-coalesced
    k_attnexp<<<(NE + 255) / 256, 256, 0, stream>>>(einfo, (const float2*)alc, (const float2*)ar, rec1);
    // 10: layer-1 gather, dense rec
    k_gather1<<<NN / 4, 256, 0, stream>>>(rowptr, rec1, (const unsigned int*)xlh,
                                          bias + 64, hbuf, scsh, out);
}

// Round 10
// 271.047 us; speedup vs baseline: 1.3124x; 1.0590x over previous
//
#include <hip/hip_runtime.h>
#include <hip/hip_fp16.h>
#include <math.h>

#define NN 20000
#define NE 320000
#define NB 128
#define SLOPE 0.2f
#define BN_EPS 1e-5f
#define NBLK 79   // ceil(NN/256)
#define PBKT 64   // BN partial bucket rows (64x128 f32 = 32KB, cheap to re-reduce per block)
#define ROWS_H 33 // half-tile LDS row stride (floats): (el+k)%32 -> 2-way, free (odd stride is load-bearing)

__device__ __forceinline__ unsigned short f2bf(float f) {
    unsigned int u = __float_as_uint(f);
    unsigned int r = (u + 0x7FFFu + ((u >> 16) & 1u)) >> 16;
    return (unsigned short)r;
}
__device__ __forceinline__ float bf2f(unsigned short h) {
    return __uint_as_float(((unsigned int)h) << 16);
}

// ---------- fused front: hist (0..1249) + insl (1250..1377) + ve/ce (1378..1379) ----------
__global__ __launch_bounds__(256) void k_front(const int* __restrict__ dst, int* __restrict__ deg,
                                               const float* __restrict__ instr, const float* __restrict__ Wl,
                                               const float* __restrict__ We, const float* __restrict__ atte,
                                               float* __restrict__ insl01, float* __restrict__ ve01,
                                               float* __restrict__ ce01) {
    __shared__ float w2[128];
    int blk = blockIdx.x, t = threadIdx.x;
    if (blk < 1250) {
        int e = blk * 256 + t;
        atomicAdd(&deg[dst[e]], 1);
    } else if (blk < 1378) {
        int bb = blk - 1250;
        int L = bb >> 6;
        int idx = (bb & 63) * 256 + t;
        int b = idx >> 7, j = idx & 127;
        const float* ins = instr + (size_t)L * NB * 64;
        const float* WlL = Wl + (size_t)L * 128 * 128;
        float acc = 0.f;
        for (int k = 0; k < 64; ++k) acc += ins[b * 64 + k] * WlL[(64 + k) * 128 + j];
        insl01[(size_t)L * 16384 + idx] = acc;
    } else {
        int L = blk - 1378;
        const float* WeL = We + (size_t)L * 128 * 128;
        const float* aeL = atte + L * 128;
        int h = (t >> 6) & 1;
        int k = t & 63;
        int row = (t < 128) ? k : (64 + k);
        float acc = 0.f;
        for (int c = 0; c < 64; ++c) acc += WeL[row * 128 + h * 64 + c] * aeL[h * 64 + c];
        if (t < 128) ve01[L * 128 + t] = acc;
        else        w2[t - 128] = acc;
        __syncthreads();
        int b = t >> 1, hh = t & 1;
        const float* ins = instr + (size_t)L * NB * 64;
        float a2 = 0.f;
        for (int kk = 0; kk < 64; ++kk) a2 += ins[b * 64 + kk] * w2[hh * 64 + kk];
        ce01[L * 256 + b * 2 + hh] = a2;
    }
}

// ---------- CSR scan: 2-kernel chain (proven round-9) ----------
__global__ __launch_bounds__(256) void k_scanA(const int* __restrict__ deg, int* __restrict__ bsum) {
    __shared__ int wsum[4];
    int t = threadIdx.x;
    int idx = blockIdx.x * 256 + t;
    int v = (idx < NN) ? deg[idx] : 0;
    for (int off = 32; off > 0; off >>= 1) v += __shfl_xor(v, off);
    if ((t & 63) == 0) wsum[t >> 6] = v;
    __syncthreads();
    if (t == 0) bsum[blockIdx.x] = wsum[0] + wsum[1] + wsum[2] + wsum[3];
}

__global__ __launch_bounds__(256) void k_scanC(const int* __restrict__ deg, const int* __restrict__ bsum,
                                               int* __restrict__ rowptr, int* __restrict__ cursor) {
    __shared__ int wsum[4];
    __shared__ int sboff;
    int t = threadIdx.x, lane = t & 63, w = t >> 6;
    int blk = blockIdx.x;
    if (t < 64) {   // wave-uniform branch: wave 0 computes this block's global offset
        int b0 = (lane < NBLK) ? bsum[lane] : 0;
        int b1 = (64 + lane < NBLK) ? bsum[64 + lane] : 0;
        int m = ((lane < blk) ? b0 : 0) + ((64 + lane < blk) ? b1 : 0);
        for (int off = 32; off > 0; off >>= 1) m += __shfl_xor(m, off);
        if (lane == 0) sboff = m;
        if (blk == 0) {
            int tt = b0 + b1;
            for (int off = 32; off > 0; off >>= 1) tt += __shfl_xor(tt, off);
            if (lane == 0) rowptr[NN] = tt;
        }
    }
    int idx = blk * 256 + t;
    int v = (idx < NN) ? deg[idx] : 0;
    int incl = v;
    for (int off = 1; off < 64; off <<= 1) { int u = __shfl_up(incl, off); if (lane >= off) incl += u; }
    if (lane == 63) wsum[w] = incl;
    __syncthreads();
    int pre = 0;
    for (int i = 0; i < w; ++i) pre += wsum[i];
    int excl = incl - v + pre + sboff;
    if (idx < NN) { rowptr[idx] = excl; cursor[idx] = excl; }
}

// ---------- node linear: xl (bf16) + alc + ar; BN finalize folded in (use_bn: per-block re-reduce) ----------
__global__ __launch_bounds__(256) void k_node(const float* __restrict__ hcur, const float* __restrict__ Wl,
                                              const float* __restrict__ insl, const int* __restrict__ batch,
                                              const float* __restrict__ attl, const float* __restrict__ attr_,
                                              const float2* __restrict__ ce2,
                                              const float* __restrict__ part,
                                              const float* __restrict__ bn_g, const float* __restrict__ bn_b,
                                              int use_bn,
                                              float* __restrict__ scsh_out,
                                              unsigned short* __restrict__ xlh,
                                              float* __restrict__ alc, float* __restrict__ ar) {
    __shared__ float sh[8 * 64];
    __shared__ float red[256];
    __shared__ float scsh_s[128];
    int t = threadIdx.x;
    if (use_bn) {
        // re-reduce 64x128 BN partials (L2-hot, ~32KB) -> scale/shift in LDS
        int col = t & 127, half = t >> 7;
        float s = 0.f;
        for (int r = half * (PBKT / 2); r < (half + 1) * (PBKT / 2); ++r) s += part[r * 128 + col];
        red[t] = s;
        __syncthreads();
        if (t < 64) {
            float su = red[t] + red[t + 128];            // col t      = sum
            float sq = red[t + 64] + red[t + 192];       // col 64+t   = sumsq
            float mu = su * (1.f / NN);
            float var = sq * (1.f / NN) - mu * mu;
            float sc = bn_g[t] * rsqrtf(var + BN_EPS);
            scsh_s[t] = sc;
            scsh_s[64 + t] = bn_b[t] - mu * sc;
            if (blockIdx.x == 0) {                        // persist for k_gather1
                scsh_out[t] = sc;
                scsh_out[64 + t] = scsh_s[64 + t];
            }
        }
        __syncthreads();
    }
    int row0 = blockIdx.x * 8;
    for (int idx = t; idx < 512; idx += 256) {
        int r = idx >> 6, k = idx & 63;
        int n = row0 + r;
        float hv = (n < NN) ? hcur[n * 64 + k] : 0.f;
        if (use_bn) hv = fmaxf(hv * scsh_s[k] + scsh_s[64 + k], 0.f);
        sh[idx] = hv;
    }
    __syncthreads();
    int w = t >> 6, lane = t & 63;
    int h = w & 1;
    int rbase = (w >> 1) * 4;
    int j = h * 64 + lane;
    float attlv = attl[j];
    float attrv = attr_[j];
    float acc0 = 0.f, acc1 = 0.f, acc2 = 0.f, acc3 = 0.f;
    for (int k = 0; k < 64; ++k) {
        float wv = Wl[k * 128 + j];
        acc0 += sh[(rbase + 0) * 64 + k] * wv;
        acc1 += sh[(rbase + 1) * 64 + k] * wv;
        acc2 += sh[(rbase + 2) * 64 + k] * wv;
        acc3 += sh[(rbase + 3) * 64 + k] * wv;
    }
    float accs[4] = {acc0, acc1, acc2, acc3};
    for (int rr = 0; rr < 4; ++rr) {
        int n = row0 + rbase + rr;
        if (n >= NN) break;
        int b = batch[n];
        float v = accs[rr] + insl[b * 128 + j];
        xlh[(size_t)n * 128 + j] = f2bf(v);
        float pl = v * attlv, pr = v * attrv;
        for (int off = 32; off > 0; off >>= 1) {
            pl += __shfl_xor(pl, off);
            pr += __shfl_xor(pr, off);
        }
        if (lane == 0) {
            float2 cb = ce2[b];
            alc[n * 2 + h] = pl + (h ? cb.y : cb.x);
            ar[n * 2 + h] = pr;
        }
    }
}

// ---------- edge kernel v5 (proven): half-tile LDS staging + in-kernel svT transpose ----------
__global__ __launch_bounds__(64) void k_sced(const int* __restrict__ src, const int* __restrict__ dst,
                                             const float* __restrict__ eattr, const float* __restrict__ ve01,
                                             const float2* __restrict__ alc2, const float2* __restrict__ ar2,
                                             int* __restrict__ cursor, int4* __restrict__ einfo) {
    __shared__ float se[64 * ROWS_H];   // 8448 B
    __shared__ float svT[256];          // 1 KB
    int lane = threadIdx.x;
#pragma unroll
    for (int i = 0; i < 4; ++i) {
        int idx = i * 64 + lane;
        svT[idx] = ve01[(idx & 3) * 64 + (idx >> 2)];   // svT[4k+j] = ve01[j*64+k]
    }
    int ebase = blockIdx.x * 64;
    float d0 = 0.f, d1 = 0.f, d2 = 0.f, d3 = 0.f;
    const float* row = se + lane * ROWS_H;
#pragma unroll
    for (int half = 0; half < 2; ++half) {
        const float4* gsrc = (const float4*)eattr + (size_t)ebase * 16 + half * 8;
#pragma unroll
        for (int i = 0; i < 8; ++i) {
            int fi = i * 64 + lane;
            int el = fi >> 3, q = fi & 7;
            float4 f = gsrc[(size_t)el * 16 + q];
            float* dp = se + el * ROWS_H + q * 4;
            dp[0] = f.x; dp[1] = f.y; dp[2] = f.z; dp[3] = f.w;
        }
        const float* vbase = svT + half * 128;
#pragma unroll
        for (int k = 0; k < 32; ++k) {
            float fv = row[k];
            float4 vt = *(const float4*)&vbase[4 * k];
            d0 += fv * vt.x; d1 += fv * vt.y; d2 += fv * vt.z; d3 += fv * vt.w;
        }
    }
    int e = ebase + lane;
    int s = src[e], dd = dst[e];
    float2 al = alc2[s], arr = ar2[dd];
    float a0 = al.x + arr.x + d0;
    float a1 = al.y + arr.y + d1;
    a0 = (a0 > 0.f) ? a0 : SLOPE * a0;
    a1 = (a1 > 0.f) ? a1 : SLOPE * a1;
    __half2 ex = __floats2half2_rn(__expf(a0), __expf(a1));
    __half2 d23 = __floats2half2_rn(d2, d3);
    int pos = atomicAdd(&cursor[dd], 1);
    einfo[pos] = make_int4(s | (dd << 15), *(int*)&d23, s, *(int*)&ex);
}

// ---------- layer-0 gather: weighted mean + bias + residual; BN partials via fence-free atomics ----------
__global__ __launch_bounds__(256) void k_gather0(const int* __restrict__ rowptr, const int2* __restrict__ rec,
                                                 const unsigned int* __restrict__ xl32,
                                                 const float* __restrict__ bias, const float* __restrict__ hprev,
                                                 float* __restrict__ hnew, float* __restrict__ part) {
    __shared__ float smv[4][64];
    __shared__ float smq[4][64];
    int t = threadIdx.x;
    int w = t >> 6, lane = t & 63;
    int n = blockIdx.x * 4 + w;
    int r0 = rowptr[n], r1 = rowptr[n + 1];
    float acc0 = 0.f, acc1 = 0.f, ss = 0.f;
    const unsigned int* xlp = xl32 + lane;
#pragma unroll 8
    for (int p = r0; p < r1; ++p) {
        int2 r = rec[(size_t)p * 2];
        __half2 hx = *(__half2*)&r.y;
        float2 e2 = __half22float2(hx);
        float ex = (lane < 32) ? e2.x : e2.y;
        unsigned int pr = xlp[(size_t)r.x * 64];
        ss += ex;
        acc0 += ex * bf2f((unsigned short)(pr & 0xFFFFu));
        acc1 += ex * bf2f((unsigned short)(pr >> 16));
    }
    float inv_s = 1.f / (ss + 1e-16f);
    acc0 *= inv_s; acc1 *= inv_s;
    float o0 = 0.5f * (acc0 + __shfl_xor(acc0, 32));
    float o1 = 0.5f * (acc1 + __shfl_xor(acc1, 32));
    if (lane < 32) {
        float2 hv = ((const float2*)(hprev + (size_t)n * 64))[lane];
        float2 bv = ((const float2*)bias)[lane];
        float2 o;
        o.x = o0 + bv.x + hv.x;
        o.y = o1 + bv.y + hv.y;
        ((float2*)(hnew + (size_t)n * 64))[lane] = o;
        smv[w][2 * lane]     = o.x;
        smv[w][2 * lane + 1] = o.y;
        smq[w][2 * lane]     = o.x * o.x;
        smq[w][2 * lane + 1] = o.y * o.y;
    }
    __syncthreads();
    // fence-free: kernel boundary before the layer-1 k_node provides visibility
    if (t < 128) {
        int c = t & 63, which = t >> 6;
        float a = which ? (smq[0][c] + smq[1][c] + smq[2][c] + smq[3][c])
                        : (smv[0][c] + smv[1][c] + smv[2][c] + smv[3][c]);
        atomicAdd(&part[(blockIdx.x & (PBKT - 1)) * 128 + which * 64 + c], a);
    }
}

// ---------- layer-1 logits + exp (CSR order, coalesced read/write) ----------
__global__ __launch_bounds__(256) void k_attnexp(const int4* __restrict__ einfo,
                                                 const float2* __restrict__ alc2, const float2* __restrict__ ar2,
                                                 int2* __restrict__ rec1) {
    int p = blockIdx.x * 256 + threadIdx.x;
    if (p >= NE) return;
    int4 r = einfo[p];
    int s = r.x & 0x7FFF, d = r.x >> 15;
    __half2 hd = *(__half2*)&r.y;
    float2 dv = __half22float2(hd);
    float2 a_l = alc2[s];
    float2 a_r = ar2[d];
    float a0 = a_l.x + a_r.x + dv.x;
    float a1 = a_l.y + a_r.y + dv.y;
    a0 = (a0 > 0.f) ? a0 : SLOPE * a0;
    a1 = (a1 > 0.f) ? a1 : SLOPE * a1;
    __half2 hx = __floats2half2_rn(__expf(a0), __expf(a1));
    rec1[p] = make_int2(s, *(int*)&hx);
}

// ---------- layer-1 gather: dense 8B rec; BN'd residual ----------
__global__ __launch_bounds__(256) void k_gather1(const int* __restrict__ rowptr, const int2* __restrict__ rec,
                                                 const unsigned int* __restrict__ xl32,
                                                 const float* __restrict__ bias, const float* __restrict__ hprev,
                                                 const float* __restrict__ scsh, float* __restrict__ out) {
    int t = threadIdx.x;
    int w = t >> 6, lane = t & 63;
    int n = blockIdx.x * 4 + w;
    int r0 = rowptr[n], r1 = rowptr[n + 1];
    float acc0 = 0.f, acc1 = 0.f, ss = 0.f;
    const unsigned int* xlp = xl32 + lane;
#pragma unroll 8
    for (int p = r0; p < r1; ++p) {
        int2 r = rec[p];
        __half2 hx = *(__half2*)&r.y;
        float2 e2 = __half22float2(hx);
        float ex = (lane < 32) ? e2.x : e2.y;
        unsigned int pr = xlp[(size_t)r.x * 64];
        ss += ex;
        acc0 += ex * bf2f((unsigned short)(pr & 0xFFFFu));
        acc1 += ex * bf2f((unsigned short)(pr >> 16));
    }
    float inv_s = 1.f / (ss + 1e-16f);
    acc0 *= inv_s; acc1 *= inv_s;
    float o0 = 0.5f * (acc0 + __shfl_xor(acc0, 32));
    float o1 = 0.5f * (acc1 + __shfl_xor(acc1, 32));
    if (lane < 32) {
        float2 hv = ((const float2*)(hprev + (size_t)n * 64))[lane];
        float2 sc = ((const float2*)scsh)[lane];
        float2 sf = ((const float2*)(scsh + 64))[lane];
        hv.x = fmaxf(hv.x * sc.x + sf.x, 0.f);
        hv.y = fmaxf(hv.y * sc.y + sf.y, 0.f);
        float2 bv = ((const float2*)bias)[lane];
        float2 o;
        o.x = o0 + bv.x + hv.x;
        o.y = o1 + bv.y + hv.y;
        ((float2*)(out + (size_t)n * 64))[lane] = o;
    }
}

extern "C" void kernel_launch(void* const* d_in, const int* in_sizes, int n_in,
                              void* d_out, int out_size, void* d_ws, size_t ws_size,
                              hipStream_t stream) {
    (void)in_sizes; (void)n_in; (void)out_size; (void)ws_size;
    const float* x     = (const float*)d_in[0];
    const int*   eidx  = (const int*)d_in[1];
    const float* eattr = (const float*)d_in[2];
    const float* instr = (const float*)d_in[3];
    const int*   batch = (const int*)d_in[4];
    const float* W_l   = (const float*)d_in[5];
    const float* W_e   = (const float*)d_in[6];
    const float* att_l = (const float*)d_in[7];
    const float* att_r = (const float*)d_in[8];
    const float* att_e = (const float*)d_in[9];
    const float* bias  = (const float*)d_in[10];
    const float* bn_g  = (const float*)d_in[11];
    const float* bn_b  = (const float*)d_in[12];
    float* out = (float*)d_out;

    const int* src = eidx;
    const int* dst = eidx + NE;

    char* ws = (char*)d_ws;
    int4*   einfo   = (int4*)ws;       ws += (size_t)NE * 16;
    int2*   rec1    = (int2*)ws;       ws += (size_t)NE * 8;
    unsigned short* xlh = (unsigned short*)ws; ws += (size_t)NN * 128 * 2;
    int*    deg     = (int*)ws;        ws += NN * 4;                 // |-- zeroed as one
    float*  part    = (float*)ws;      ws += PBKT * 128 * 4;         // |   contiguous memset region
    int*    rowptr  = (int*)ws;        ws += (NN + 1) * 4 + 12;
    int*    cursor  = (int*)ws;        ws += NN * 4;
    int*    bsum    = (int*)ws;        ws += 80 * 4;
    float*  alc     = (float*)ws;      ws += NN * 2 * 4;
    float*  ar      = (float*)ws;      ws += NN * 2 * 4;
    float*  insl01  = (float*)ws;      ws += 2 * 128 * 128 * 4;
    float*  ve01    = (float*)ws;      ws += 256 * 4;
    float*  ce01    = (float*)ws;      ws += 2 * 256 * 4;
    float*  hbuf    = (float*)ws;      ws += (size_t)NN * 64 * 4;
    float*  scsh    = (float*)ws;      ws += 128 * 4;

    hipMemsetAsync(deg, 0, NN * 4 + PBKT * 128 * 4, stream);

    // 1: hist + insl + ve/ce precompute
    k_front<<<1380, 256, 0, stream>>>(dst, deg, instr, W_l, W_e, att_e, insl01, ve01, ce01);
    // 2-3: CSR rowptr/cursor
    k_scanA<<<NBLK, 256, 0, stream>>>(deg, bsum);
    k_scanC<<<NBLK, 256, 0, stream>>>(deg, bsum, rowptr, cursor);
    // 4: layer-0 node linear (no BN)
    k_node<<<(NN + 7) / 8, 256, 0, stream>>>(x, W_l, insl01, batch,
                                             att_l, att_r, (const float2*)ce01,
                                             part, bn_g, bn_b, 0, scsh, xlh, alc, ar);
    // 5: edge dots (both layers) + L0 logits; half-tile staging
    k_sced<<<NE / 64, 64, 0, stream>>>(src, dst, eattr, ve01,
                                       (const float2*)alc, (const float2*)ar, cursor, einfo);
    // 6: layer-0 gather + fence-free BN partial atomics
    k_gather0<<<NN / 4, 256, 0, stream>>>(rowptr, (const int2*)einfo + 1,
                                          (const unsigned int*)xlh, bias, x, hbuf, part);
    // 7: layer-1 node linear (BN finalize folded in; block 0 persists scsh for gather1)
    k_node<<<(NN + 7) / 8, 256, 0, stream>>>(hbuf, W_l + 128 * 128, insl01 + 16384, batch,
                                             att_l + 128, att_r + 128, (const float2*)(ce01 + 256),
                                             part, bn_g, bn_b, 1, scsh, xlh, alc, ar);
    // 8: layer-1 logits+exp, CSR-coalesced
    k_attnexp<<<(NE + 255) / 256, 256, 0, stream>>>(einfo, (const float2*)alc, (const float2*)ar, rec1);
    // 9: layer-1 gather, dense rec
    k_gather1<<<NN / 4, 256, 0, stream>>>(rowptr, rec1, (const unsigned int*)xlh,
                                          bias + 64, hbuf, scsh, out);
}